// Round 3
// baseline (39.135 us; speedup 1.0000x reference)
//
#include <hip/hip_runtime.h>
#include <math.h>

#define N_T   16384
#define BLOCK 1024
#define SEG   (N_T / BLOCK)   // 16 elements per thread
#define NWAVE (BLOCK / 64)    // 16 waves

// XOR-swizzle word index: mix bits [6:8] into bits [2:4].
// Preserves 16B (float4) granularity; bijective within [0, 16384).
__device__ __forceinline__ int SW(int i) {
    return i ^ (((i >> 6) & 7) << 2);
}

// MODE 0: d_out = real part only, flat (16,64,16384) float32  (out_size = N)
// MODE 1: d_out = interleaved re/im pairs                     (out_size = 2N)
template <int MODE>
__global__ __launch_bounds__(BLOCK)
void phase_kernel(const float* __restrict__ x, float* __restrict__ out) {
    __shared__ float ph[N_T];   // exactly 64 KiB static LDS

    const int tid  = threadIdx.x;
    const int lane = tid & 63;
    const int wave = tid >> 6;
    const int r    = blockIdx.x;         // row in [0, 1024)
    const int b    = r >> 6;             // batch
    const int c    = r & 63;             // channel
    const float* __restrict__ phase_row = x + ((size_t)(b * 128 + 64 + c)) * N_T;
    const float* __restrict__ mag_row   = x + ((size_t)(b * 128 + c)) * N_T;

    const float TWO_PI = 6.28318530717958647692f;  // f32 0x40C90FDB
    const float PI_F   = 3.14159265358979323846f;
    const float THIRD  = 1.0f / 3.0f;

    // ---- 1. stage phase row into LDS (swizzled), coalesced float4 loads
    #pragma unroll
    for (int i = 0; i < N_T / (BLOCK * 4); ++i) {   // 4 iters
        int idx = (i * BLOCK + tid) * 4;
        float4 v = *reinterpret_cast<const float4*>(phase_row + idx);
        *reinterpret_cast<float4*>(&ph[SW(idx)]) = v;
    }
    __syncthreads();

    // ---- 2. own contiguous segment into registers; local d-sum
    const int seg0 = tid * SEG;
    float s[SEG];
    #pragma unroll
    for (int q = 0; q < SEG / 4; ++q) {             // 4 x ds_read_b128
        float4 v = *reinterpret_cast<const float4*>(&ph[SW(seg0 + q * 4)]);
        s[q * 4 + 0] = v.x; s[q * 4 + 1] = v.y;
        s[q * 4 + 2] = v.z; s[q * 4 + 3] = v.w;
    }
    float prevseg = __shfl_up(s[SEG - 1], 1);       // last elem of prev thread
    if (lane == 0) prevseg = (tid > 0) ? ph[SW(seg0 - 1)] : 0.0f;

    int lsum = 0;
    {
        float prev = prevseg;
        #pragma unroll
        for (int j = 0; j < SEG; ++j) {
            float g = s[j] - prev;
            if ((seg0 + j) > 0 && fabsf(g) > 0.5f) lsum += (g > 0.0f) ? 1 : -1;
            prev = s[j];
        }
    }

    // ---- 3. block-wide exclusive scan of lsum
    int incl = lsum;
    #pragma unroll
    for (int off = 1; off < 64; off <<= 1) {
        int n = __shfl_up(incl, off);
        if (lane >= off) incl += n;
    }
    float saved;
    if (tid < NWAVE) saved = ph[tid];               // SW(j)==j for j<64
    __syncthreads();
    if (lane == 63) ph[wave] = __int_as_float(incl);
    __syncthreads();
    int wpre = 0;
    #pragma unroll
    for (int w = 0; w < NWAVE; ++w) {
        int wt = __float_as_int(ph[w]);             // broadcast read
        if (w < wave) wpre += wt;
    }
    __syncthreads();
    if (tid < NWAVE) ph[tid] = saved;
    __syncthreads();

    int running = wpre + incl - lsum;               // corr at seg0 (exclusive)

    // ---- 4. corrected phase in registers, write back (float4, swizzled)
    {
        float prev = prevseg;
        #pragma unroll
        for (int j = 0; j < SEG; ++j) {
            float cur = s[j];
            int d = 0;
            if ((seg0 + j) > 0) {
                float g = cur - prev;
                if (fabsf(g) > 0.5f) d = (g > 0.0f) ? 1 : -1;
            }
            s[j] = (cur - (float)running) * TWO_PI - PI_F;
            running += d;
            prev = cur;
        }
    }
    #pragma unroll
    for (int q = 0; q < SEG / 4; ++q) {
        *reinterpret_cast<float4*>(&ph[SW(seg0 + q * 4)]) =
            make_float4(s[q * 4 + 0], s[q * 4 + 1], s[q * 4 + 2], s[q * 4 + 3]);
    }
    __syncthreads();

    // ---- 5. coalesced output pass
    #pragma unroll
    for (int i = 0; i < N_T / (BLOCK * 4); ++i) {   // 4 iters
        int e = (i * BLOCK + tid) * 4;
        float4 mg = *reinterpret_cast<const float4*>(mag_row + e);
        float4 pc = *reinterpret_cast<const float4*>(&ph[SW(e)]);

        float p_m1 = __shfl_up(pc.w, 1);
        if (lane == 0)  p_m1 = (e > 0) ? ph[SW(e - 1)] : 0.0f;       // zero pad left
        float p_p4 = __shfl_down(pc.x, 1);
        if (lane == 63) p_p4 = (e + 4 < N_T) ? ph[SW(e + 4)] : 0.0f; // zero pad right

        float pv[6] = {p_m1, pc.x, pc.y, pc.z, pc.w, p_p4};
        float mgk[4] = {mg.x, mg.y, mg.z, mg.w};

        float re[4], im[4];
        #pragma unroll
        for (int k = 0; k < 4; ++k) {
            float sm = ((pv[k] + pv[k + 1]) + pv[k + 2]) * THIRD;
            float pf = 0.7f * pv[k + 1] + 0.3f * sm;
            // two-term range reduction: 2pi = hi + lo
            float nrev = rintf(pf * 0.15915494309189535f);
            float rr = fmaf(nrev, -6.28318548202514648f, pf);
            rr = fmaf(nrev, 1.74845553e-7f, rr);
            re[k] = mgk[k] * __cosf(rr);
            if (MODE == 1) im[k] = mgk[k] * __sinf(rr);
        }
        if (MODE == 0) {
            float* orow = out + (size_t)r * N_T;
            *reinterpret_cast<float4*>(orow + e) = make_float4(re[0], re[1], re[2], re[3]);
        } else {
            float* orow = out + (size_t)r * (2 * N_T);
            *reinterpret_cast<float4*>(orow + 2 * e) =
                make_float4(re[0], im[0], re[1], im[1]);
            *reinterpret_cast<float4*>(orow + 2 * e + 4) =
                make_float4(re[2], im[2], re[3], im[3]);
        }
    }
}

extern "C" void kernel_launch(void* const* d_in, const int* in_sizes, int n_in,
                              void* d_out, int out_size, void* d_ws, size_t ws_size,
                              hipStream_t stream) {
    const float* x = (const float*)d_in[0];
    float* out = (float*)d_out;
    // in_sizes[0] = 16*128*16384 = 33,554,432; complex elements N = in_sizes[0]/2
    int n_rows = in_sizes[0] / (2 * N_T);            // 1024
    if (out_size >= in_sizes[0]) {
        // d_out holds interleaved re/im (2N floats)
        phase_kernel<1><<<n_rows, BLOCK, 0, stream>>>(x, out);
    } else {
        // d_out holds real part only (N floats) — harness cast complex->float32
        phase_kernel<0><<<n_rows, BLOCK, 0, stream>>>(x, out);
    }
}